// Round 3
// baseline (917.715 us; speedup 1.0000x reference)
//
#include <hip/hip_runtime.h>
#include <math.h>

// Problem constants (from reference): B=2, S=1024 -> T=2048 tokens
#define HDIM 1024
#define IDIM 512
#define NEXP 16
#define TOPK 4
#define NTOK 2048

// Workspace layout (bytes). Total ~21.3 MB.
#define CNT_OFF   0                                   // int[16]
#define TOK_OFF   256                                 // int[NEXP*NTOK]  packed (t<<2)|k
#define WGT_OFF   (TOK_OFF + NEXP * NTOK * 4)         // float[NEXP*NTOK]
#define HS_OFF    (WGT_OFF + NEXP * NTOK * 4)         // float[NTOK*IDIM]    shared-expert h
#define HR_OFF    (HS_OFF + NTOK * IDIM * 4)          // float[NTOK*TOPK*IDIM] routed h, row = (t<<2)|k

// ---------------------------------------------------------------------------
// Routing: scores = sigmoid(x @ gate_w^T), top-4, normalize, build per-expert
// compact token lists. One wave per token.
// ---------------------------------------------------------------------------
__global__ __launch_bounds__(64) void route_kernel(const float* __restrict__ x,
                                                   const float* __restrict__ gw,
                                                   int* __restrict__ cnt,
                                                   int* __restrict__ tok,
                                                   float* __restrict__ wgt) {
    const int t = blockIdx.x;
    const int lane = threadIdx.x;
    const float* xr = x + (size_t)t * HDIM;

    float acc[NEXP];
#pragma unroll
    for (int e = 0; e < NEXP; ++e) acc[e] = 0.f;

    for (int h = lane; h < HDIM; h += 64) {
        float xv = xr[h];
#pragma unroll
        for (int e = 0; e < NEXP; ++e) acc[e] += xv * gw[e * HDIM + h];
    }
    // butterfly reduce each expert score across the wave
#pragma unroll
    for (int e = 0; e < NEXP; ++e) {
        float v = acc[e];
#pragma unroll
        for (int off = 32; off > 0; off >>= 1) v += __shfl_xor(v, off, 64);
        acc[e] = v;
    }

    if (lane == 0) {
        float s[NEXP];
#pragma unroll
        for (int e = 0; e < NEXP; ++e) s[e] = 1.f / (1.f + expf(-acc[e]));
        bool used[NEXP];
#pragma unroll
        for (int e = 0; e < NEXP; ++e) used[e] = false;

        int id4[TOPK];
        float w4[TOPK];
        float sum = 0.f;
        for (int k = 0; k < TOPK; ++k) {
            float best = -1.f;
            int bi = 0;
            for (int e = 0; e < NEXP; ++e) {
                if (!used[e] && s[e] > best) { best = s[e]; bi = e; }
            }
            used[bi] = true;
            id4[k] = bi;
            w4[k] = best;
            sum += best;
        }
        float inv = 1.f / sum;
        for (int k = 0; k < TOPK; ++k) {
            int e = id4[k];
            int slot = atomicAdd(&cnt[e], 1);
            tok[e * NTOK + slot] = (t << 2) | k;
            wgt[e * NTOK + slot] = w4[k] * inv;
        }
    }
}

// ---------------------------------------------------------------------------
// Shared expert, up: hs = silu(x@sg) * (x@su).  M=NTOK, N=IDIM, K=HDIM.
// 64x64 tile, BK=16, 256 threads, 4x4 microtile (x2 for g and u).
// ---------------------------------------------------------------------------
__global__ __launch_bounds__(256) void shared_up(const float* __restrict__ x,
                                                 const float* __restrict__ sg,
                                                 const float* __restrict__ su,
                                                 float* __restrict__ hs) {
    __shared__ float As[16][64];
    __shared__ float Bg[16][64];
    __shared__ float Bu[16][64];
    const int m0 = blockIdx.x * 64, n0 = blockIdx.y * 64;
    const int tid = threadIdx.x;
    const int tx = tid & 15, ty = tid >> 4;

    float cg[4][4] = {{0.f}}, cu[4][4] = {{0.f}};

    for (int k0 = 0; k0 < HDIM; k0 += 16) {
#pragma unroll
        for (int i = 0; i < 4; ++i) {
            int idx = tid + i * 256;            // 0..1023 over [m][k]
            int m = idx >> 4, k = idx & 15;
            As[k][m] = x[(size_t)(m0 + m) * HDIM + k0 + k];
        }
#pragma unroll
        for (int i = 0; i < 4; ++i) {
            int idx = tid + i * 256;            // 0..1023 over [k][n]
            int k = idx >> 6, n = idx & 63;
            Bg[k][n] = sg[(size_t)(k0 + k) * IDIM + n0 + n];
            Bu[k][n] = su[(size_t)(k0 + k) * IDIM + n0 + n];
        }
        __syncthreads();
#pragma unroll
        for (int k = 0; k < 16; ++k) {
            float a[4], bg[4], bu[4];
#pragma unroll
            for (int i = 0; i < 4; ++i) a[i] = As[k][ty * 4 + i];
#pragma unroll
            for (int j = 0; j < 4; ++j) { bg[j] = Bg[k][tx * 4 + j]; bu[j] = Bu[k][tx * 4 + j]; }
#pragma unroll
            for (int i = 0; i < 4; ++i)
#pragma unroll
                for (int j = 0; j < 4; ++j) {
                    cg[i][j] += a[i] * bg[j];
                    cu[i][j] += a[i] * bu[j];
                }
        }
        __syncthreads();
    }
#pragma unroll
    for (int i = 0; i < 4; ++i)
#pragma unroll
        for (int j = 0; j < 4; ++j) {
            int m = m0 + ty * 4 + i, n = n0 + tx * 4 + j;
            float g = cg[i][j], u = cu[i][j];
            float sil = g / (1.f + expf(-g));
            hs[(size_t)m * IDIM + n] = sil * u;
        }
}

// ---------------------------------------------------------------------------
// Shared expert, down: out = hs @ sd.  M=NTOK, N=HDIM, K=IDIM. Plain store
// (initializes d_out; routed contributions are atomically added later).
// ---------------------------------------------------------------------------
__global__ __launch_bounds__(256) void shared_down(const float* __restrict__ hs,
                                                   const float* __restrict__ sd,
                                                   float* __restrict__ out) {
    __shared__ float As[16][64];
    __shared__ float Bs[16][64];
    const int m0 = blockIdx.x * 64, n0 = blockIdx.y * 64;
    const int tid = threadIdx.x;
    const int tx = tid & 15, ty = tid >> 4;

    float c[4][4] = {{0.f}};

    for (int k0 = 0; k0 < IDIM; k0 += 16) {
#pragma unroll
        for (int i = 0; i < 4; ++i) {
            int idx = tid + i * 256;
            int m = idx >> 4, k = idx & 15;
            As[k][m] = hs[(size_t)(m0 + m) * IDIM + k0 + k];
        }
#pragma unroll
        for (int i = 0; i < 4; ++i) {
            int idx = tid + i * 256;
            int k = idx >> 6, n = idx & 63;
            Bs[k][n] = sd[(size_t)(k0 + k) * HDIM + n0 + n];
        }
        __syncthreads();
#pragma unroll
        for (int k = 0; k < 16; ++k) {
            float a[4], b[4];
#pragma unroll
            for (int i = 0; i < 4; ++i) a[i] = As[k][ty * 4 + i];
#pragma unroll
            for (int j = 0; j < 4; ++j) b[j] = Bs[k][tx * 4 + j];
#pragma unroll
            for (int i = 0; i < 4; ++i)
#pragma unroll
                for (int j = 0; j < 4; ++j) c[i][j] += a[i] * b[j];
        }
        __syncthreads();
    }
#pragma unroll
    for (int i = 0; i < 4; ++i)
#pragma unroll
        for (int j = 0; j < 4; ++j)
            out[(size_t)(m0 + ty * 4 + i) * HDIM + n0 + tx * 4 + j] = c[i][j];
}

// ---------------------------------------------------------------------------
// Routed experts, up: grouped GEMM per expert over its token list.
// hr[(t<<2)|k] = silu(x_t @ Wg[e]) * (x_t @ Wu[e])
// grid = (NEXP, NTOK/64, IDIM/64); blocks past the expert's count exit.
// ---------------------------------------------------------------------------
__global__ __launch_bounds__(256) void routed_up(const float* __restrict__ x,
                                                 const float* __restrict__ Wg,
                                                 const float* __restrict__ Wu,
                                                 const int* __restrict__ cnt,
                                                 const int* __restrict__ tok,
                                                 float* __restrict__ hr) {
    const int e = blockIdx.x;
    const int nt = cnt[e];
    const int m0 = blockIdx.y * 64;
    if (m0 >= nt) return;
    const int n0 = blockIdx.z * 64;

    __shared__ int pk[64];
    __shared__ float As[16][64];
    __shared__ float Bg[16][64];
    __shared__ float Bu[16][64];

    const int tid = threadIdx.x;
    if (tid < 64) {
        int s = m0 + tid;
        pk[tid] = (s < nt) ? tok[e * NTOK + s] : -1;
    }
    __syncthreads();

    const float* wg = Wg + (size_t)e * HDIM * IDIM;
    const float* wu = Wu + (size_t)e * HDIM * IDIM;
    const int tx = tid & 15, ty = tid >> 4;

    // each thread loads the same 4 A-rows every K-step: cache their tokens
    int arow[4];
#pragma unroll
    for (int i = 0; i < 4; ++i) {
        int idx = tid + i * 256;
        int m = idx >> 4;
        int p = pk[m];
        arow[i] = (p >= 0) ? (p >> 2) : -1;
    }

    float cg[4][4] = {{0.f}}, cu[4][4] = {{0.f}};

    for (int k0 = 0; k0 < HDIM; k0 += 16) {
#pragma unroll
        for (int i = 0; i < 4; ++i) {
            int idx = tid + i * 256;
            int m = idx >> 4, k = idx & 15;
            As[k][m] = (arow[i] >= 0) ? x[(size_t)arow[i] * HDIM + k0 + k] : 0.f;
        }
#pragma unroll
        for (int i = 0; i < 4; ++i) {
            int idx = tid + i * 256;
            int k = idx >> 6, n = idx & 63;
            Bg[k][n] = wg[(size_t)(k0 + k) * IDIM + n0 + n];
            Bu[k][n] = wu[(size_t)(k0 + k) * IDIM + n0 + n];
        }
        __syncthreads();
#pragma unroll
        for (int k = 0; k < 16; ++k) {
            float a[4], bg[4], bu[4];
#pragma unroll
            for (int i = 0; i < 4; ++i) a[i] = As[k][ty * 4 + i];
#pragma unroll
            for (int j = 0; j < 4; ++j) { bg[j] = Bg[k][tx * 4 + j]; bu[j] = Bu[k][tx * 4 + j]; }
#pragma unroll
            for (int i = 0; i < 4; ++i)
#pragma unroll
                for (int j = 0; j < 4; ++j) {
                    cg[i][j] += a[i] * bg[j];
                    cu[i][j] += a[i] * bu[j];
                }
        }
        __syncthreads();
    }
#pragma unroll
    for (int i = 0; i < 4; ++i) {
        int m = ty * 4 + i;
        int p = pk[m];
        if (p >= 0) {
#pragma unroll
            for (int j = 0; j < 4; ++j) {
                float g = cg[i][j], u = cu[i][j];
                float sil = g / (1.f + expf(-g));
                hr[(size_t)p * IDIM + n0 + tx * 4 + j] = sil * u;
            }
        }
    }
}

// ---------------------------------------------------------------------------
// Routed experts, down: out[t] += w * (hr_row @ Wd[e]).  Atomic combine.
// grid = (NEXP, NTOK/64, HDIM/64)
// ---------------------------------------------------------------------------
__global__ __launch_bounds__(256) void routed_down(const float* __restrict__ hr,
                                                   const float* __restrict__ Wd,
                                                   const int* __restrict__ cnt,
                                                   const int* __restrict__ tok,
                                                   const float* __restrict__ wgt,
                                                   float* __restrict__ out) {
    const int e = blockIdx.x;
    const int nt = cnt[e];
    const int m0 = blockIdx.y * 64;
    if (m0 >= nt) return;
    const int n0 = blockIdx.z * 64;

    __shared__ int pk[64];
    __shared__ float wts[64];
    __shared__ float As[16][64];
    __shared__ float Bs[16][64];

    const int tid = threadIdx.x;
    if (tid < 64) {
        int s = m0 + tid;
        pk[tid] = (s < nt) ? tok[e * NTOK + s] : -1;
        wts[tid] = (s < nt) ? wgt[e * NTOK + s] : 0.f;
    }
    __syncthreads();

    const float* wd = Wd + (size_t)e * IDIM * HDIM;
    const int tx = tid & 15, ty = tid >> 4;

    int arow[4];
#pragma unroll
    for (int i = 0; i < 4; ++i) {
        int idx = tid + i * 256;
        arow[i] = pk[idx >> 4];
    }

    float c[4][4] = {{0.f}};

    for (int k0 = 0; k0 < IDIM; k0 += 16) {
#pragma unroll
        for (int i = 0; i < 4; ++i) {
            int idx = tid + i * 256;
            int m = idx >> 4, k = idx & 15;
            As[k][m] = (arow[i] >= 0) ? hr[(size_t)(arow[i]) * IDIM + k0 + k] : 0.f;
        }
#pragma unroll
        for (int i = 0; i < 4; ++i) {
            int idx = tid + i * 256;
            int k = idx >> 6, n = idx & 63;
            Bs[k][n] = wd[(size_t)(k0 + k) * HDIM + n0 + n];
        }
        __syncthreads();
#pragma unroll
        for (int k = 0; k < 16; ++k) {
            float a[4], b[4];
#pragma unroll
            for (int i = 0; i < 4; ++i) a[i] = As[k][ty * 4 + i];
#pragma unroll
            for (int j = 0; j < 4; ++j) b[j] = Bs[k][tx * 4 + j];
#pragma unroll
            for (int i = 0; i < 4; ++i)
#pragma unroll
                for (int j = 0; j < 4; ++j) c[i][j] += a[i] * b[j];
        }
        __syncthreads();
    }
#pragma unroll
    for (int i = 0; i < 4; ++i) {
        int m = ty * 4 + i;
        int p = pk[m];
        if (p >= 0) {
            int t = p >> 2;
            float w = wts[m];
#pragma unroll
            for (int j = 0; j < 4; ++j)
                atomicAdd(&out[(size_t)t * HDIM + n0 + tx * 4 + j], w * c[i][j]);
        }
    }
}

// ---------------------------------------------------------------------------
extern "C" void kernel_launch(void* const* d_in, const int* in_sizes, int n_in,
                              void* d_out, int out_size, void* d_ws, size_t ws_size,
                              hipStream_t stream) {
    const float* x  = (const float*)d_in[0];   // [T,H]
    const float* gw = (const float*)d_in[1];   // [E,H]
    const float* Wg = (const float*)d_in[2];   // [E,H,I]
    const float* Wu = (const float*)d_in[3];   // [E,H,I]
    const float* Wd = (const float*)d_in[4];   // [E,I,H]
    const float* sg = (const float*)d_in[5];   // [H,I]
    const float* su = (const float*)d_in[6];   // [H,I]
    const float* sd = (const float*)d_in[7];   // [I,H]
    float* out = (float*)d_out;

    char* ws = (char*)d_ws;
    int* cnt   = (int*)(ws + CNT_OFF);
    int* tok   = (int*)(ws + TOK_OFF);
    float* wgt = (float*)(ws + WGT_OFF);
    float* hs  = (float*)(ws + HS_OFF);
    float* hr  = (float*)(ws + HR_OFF);

    // cnt must be zeroed every call (ws is poisoned to 0xAA before each launch)
    hipMemsetAsync(cnt, 0, NEXP * sizeof(int), stream);

    route_kernel<<<NTOK, 64, 0, stream>>>(x, gw, cnt, tok, wgt);
    shared_up<<<dim3(NTOK / 64, IDIM / 64), 256, 0, stream>>>(x, sg, su, hs);
    shared_down<<<dim3(NTOK / 64, HDIM / 64), 256, 0, stream>>>(hs, sd, out);
    routed_up<<<dim3(NEXP, NTOK / 64, IDIM / 64), 256, 0, stream>>>(x, Wg, Wu, cnt, tok, hr);
    routed_down<<<dim3(NEXP, NTOK / 64, HDIM / 64), 256, 0, stream>>>(hr, Wd, cnt, tok, wgt, out);
}